// Round 19
// baseline (51.453 us; speedup 1.0000x reference)
//
#include <hip/hip_runtime.h>

typedef _Float16 f16;
typedef __attribute__((ext_vector_type(2))) __fp16 fp16x2;
typedef __attribute__((ext_vector_type(8))) _Float16 f16x8;
typedef __attribute__((ext_vector_type(4))) float f32x4;
typedef __attribute__((ext_vector_type(4))) unsigned int u32x4;

#define NPTS   (16 * 32768)
// packed-weight layout in d_ws (bytes); weights stay in global (L2-resident, ~80KB)
#define W0P_OFF 0
#define W1P_OFF (16 * 1024)
#define W2P_OFF (48 * 1024)
#define WOP_OFF (80 * 1024)
#define FRAGS_BYTES (84 * 1024)
#define B0E_OFF FRAGS_BYTES           // in ws: 16 batches x 128 f32 effective layer-0 bias
#define WS_NEEDED (FRAGS_BYTES + 8192)
// LDS: one wave per block -> single 4KB transpose scratch
#define LDS_TOTAL 4096

// ---------------- pack kernel: weights -> f16 A-operand fragments (W^T) ----------------
// A frag (mt,kt): lane l, elem j <-> W_sw[m = 16mt + (l&15)][k] = W[k][m]
//   layer0 (natural k-map): k = 32kt + 8*(l>>4) + j ; covers the 39 xyz dims
//     (orig W0 row = 16 + k; tenc rows folded into b0_eff, blocks 84..115)
//   layers 1,2,out (chained from D layout): k = 32kt + 16*(j>>2) + 4*(l>>4) + (j&3)
__global__ void pack_weights(const float* __restrict__ time, const float* __restrict__ te0,
                             const float* __restrict__ te1, const float* __restrict__ W0,
                             const float* __restrict__ b0, const float* __restrict__ W1,
                             const float* __restrict__ W2, const float* __restrict__ Wout,
                             unsigned char* __restrict__ ws) {
  const int bi = blockIdx.x;
  const int l = threadIdx.x;
  const int g = l >> 4, r16 = l & 15;
  if (bi < 84) {
    const float* W; int obase, fi, kt, mt, kmax; bool natural, outcol;
    if (bi < 16)      { W = W0;   fi = bi;      mt = fi >> 1; kt = fi & 1; obase = W0P_OFF; kmax = 39;  natural = true;  outcol = false; }
    else if (bi < 48) { W = W1;   fi = bi - 16; mt = fi >> 2; kt = fi & 3; obase = W1P_OFF; kmax = 128; natural = false; outcol = false; }
    else if (bi < 80) { W = W2;   fi = bi - 48; mt = fi >> 2; kt = fi & 3; obase = W2P_OFF; kmax = 128; natural = false; outcol = false; }
    else              { W = Wout; fi = bi - 80; mt = 0;       kt = fi;     obase = WOP_OFF; kmax = 128; natural = false; outcol = true;  }
    const int m = mt * 16 + r16;
    f16 vals[8] __attribute__((aligned(16)));
#pragma unroll
    for (int j = 0; j < 8; ++j) {
      const int k = natural ? (kt * 32 + g * 8 + j)
                            : (kt * 32 + (j >> 2) * 16 + g * 4 + (j & 3));
      float v = 0.f;
      if (k < kmax) {
        if (outcol)       v = (m == 0) ? Wout[k] : 0.f;
        else if (natural) v = W[(16 + k) * 128 + m];   // layer0: skip tenc rows
        else              v = W[k * 128 + m];
      }
      vals[j] = (f16)v;
    }
    *(u32x4*)(ws + obase + (fi * 64 + l) * 16) = *(const u32x4*)vals;
  } else {
    // b0_eff[b][m] = b0[m] + sum_d tenc[b][d] * W0[d][m],  d = 0..15 (orig rows)
    const int idx = (bi - 84) * 64 + l;  // 0..2047
    const int b = idx >> 7, m = idx & 127;
    const float t = time[b];
    float acc = b0[m];
#pragma unroll
    for (int d = 0; d < 16; ++d) {
      const float* emb; int L, dd;
      if (d < 8) { emb = te0; L = 5;  dd = d; }
      else       { emb = te1; L = 20; dd = d - 8; }
      const float tL = t * (float)L;
      int i = (int)floorf(tL);
      i = i < 0 ? 0 : (i > L - 1 ? L - 1 : i);
      const float wlo = (float)(i + 1) - tL;
      float v = wlo * emb[i * 8 + dd] + (1.f - wlo) * emb[(i + 1) * 8 + dd];
      if (t >= 1.f) v = emb[L * 8 + dd];
      acc += v * W0[d * 128 + m];
    }
    ((float*)(ws + B0E_OFF))[b * 128 + m] = acc;
  }
}

// packed relu: max of two f16 halves vs 0 (exact: relu commutes with RTZ rounding)
__device__ __forceinline__ unsigned int pkmax0(unsigned int x) {
  unsigned int r;
  asm("v_pk_max_f16 %0, %1, %2" : "=v"(r) : "v"(x), "v"(0u));
  return r;
}
__device__ __forceinline__ unsigned int pkrtz(float a, float b) {
  union { fp16x2 h; unsigned int u; } c;
  c.h = __builtin_amdgcn_cvt_pkrtz(a, b);
  return c.u;
}
// HW transcendentals: v_sin/v_cos take revolutions (input * 2pi). x in [0,1] here.
__device__ __forceinline__ float hwsin_rev(float rev) {
  float r; asm("v_sin_f32 %0, %1" : "=v"(r) : "v"(rev)); return r;
}
__device__ __forceinline__ float hwcos_rev(float rev) {
  float r; asm("v_cos_f32 %0, %1" : "=v"(r) : "v"(rev)); return r;
}

// ---------------- dual-task swapped layer: one weight stream feeds TWO 64-pt tasks ----------------
// Per step: 2 A-frag loads -> 16 MFMAs (8 per task). Weight traffic per point HALVES
// vs the single-task layer; load-latency cover per step doubles (~78 cyc of MFMA).
// Bias rides as C-init, shared by both tasks. Epilogue = pkrtz + pk_max.
template <int KT>
__device__ __forceinline__ void layer_dual(const unsigned char* __restrict__ wsrc,
                                           const float* __restrict__ bias,
                                           const f16x8 (&Bin0)[KT][4], const f16x8 (&Bin1)[KT][4],
                                           f16x8 (&Bout0)[4][4], f16x8 (&Bout1)[4][4],
                                           int lane) {
  const int g4 = (lane >> 4) * 4;
  f16x8 A0b[3], A1b[3];
  float4 ba, bb;
  f32x4 acc0[2][4], acc1[2][4];
  // prologue: preload steps 0,1
#pragma unroll
  for (int s = 0; s < 2; ++s) {
    const int mtp = s / KT, kt = s % KT;
    A0b[s] = *(const f16x8*)(wsrc + (((2 * mtp)     * KT + kt) * 64 + lane) * 16);
    A1b[s] = *(const f16x8*)(wsrc + (((2 * mtp + 1) * KT + kt) * 64 + lane) * 16);
  }
#pragma unroll
  for (int s = 0; s < 4 * KT; ++s) {
    const int mtp = s / KT, kt = s % KT, cb = s % 3;
    if (kt == 0) {
      ba = *(const float4*)(bias + mtp * 32 + g4);
      bb = *(const float4*)(bias + mtp * 32 + 16 + g4);
#pragma unroll
      for (int nt = 0; nt < 4; ++nt) {
        acc0[0][nt] = (f32x4){ba.x, ba.y, ba.z, ba.w};
        acc0[1][nt] = (f32x4){bb.x, bb.y, bb.z, bb.w};
        acc1[0][nt] = (f32x4){ba.x, ba.y, ba.z, ba.w};
        acc1[1][nt] = (f32x4){bb.x, bb.y, bb.z, bb.w};
      }
    }
    // prefetch step s+2
    if (s + 2 < 4 * KT) {
      const int mtp2 = (s + 2) / KT, kt2 = (s + 2) % KT, pb = (s + 2) % 3;
      A0b[pb] = *(const f16x8*)(wsrc + (((2 * mtp2)     * KT + kt2) * 64 + lane) * 16);
      A1b[pb] = *(const f16x8*)(wsrc + (((2 * mtp2 + 1) * KT + kt2) * 64 + lane) * 16);
    }
    __builtin_amdgcn_s_setprio(1);
#pragma unroll
    for (int nt = 0; nt < 4; ++nt)
      acc0[0][nt] = __builtin_amdgcn_mfma_f32_16x16x32_f16(A0b[cb], Bin0[kt][nt], acc0[0][nt], 0, 0, 0);
#pragma unroll
    for (int nt = 0; nt < 4; ++nt)
      acc1[0][nt] = __builtin_amdgcn_mfma_f32_16x16x32_f16(A0b[cb], Bin1[kt][nt], acc1[0][nt], 0, 0, 0);
#pragma unroll
    for (int nt = 0; nt < 4; ++nt)
      acc0[1][nt] = __builtin_amdgcn_mfma_f32_16x16x32_f16(A1b[cb], Bin0[kt][nt], acc0[1][nt], 0, 0, 0);
#pragma unroll
    for (int nt = 0; nt < 4; ++nt)
      acc1[1][nt] = __builtin_amdgcn_mfma_f32_16x16x32_f16(A1b[cb], Bin1[kt][nt], acc1[1][nt], 0, 0, 0);
    __builtin_amdgcn_s_setprio(0);
    if (kt == KT - 1) {
#pragma unroll
      for (int nt = 0; nt < 4; ++nt) {
        union { unsigned int w[4]; f16x8 v; } u0, u1;
        u0.w[0] = pkmax0(pkrtz(acc0[0][nt][0], acc0[0][nt][1]));
        u0.w[1] = pkmax0(pkrtz(acc0[0][nt][2], acc0[0][nt][3]));
        u0.w[2] = pkmax0(pkrtz(acc0[1][nt][0], acc0[1][nt][1]));
        u0.w[3] = pkmax0(pkrtz(acc0[1][nt][2], acc0[1][nt][3]));
        u1.w[0] = pkmax0(pkrtz(acc1[0][nt][0], acc1[0][nt][1]));
        u1.w[1] = pkmax0(pkrtz(acc1[0][nt][2], acc1[0][nt][3]));
        u1.w[2] = pkmax0(pkrtz(acc1[1][nt][0], acc1[1][nt][1]));
        u1.w[3] = pkmax0(pkrtz(acc1[1][nt][2], acc1[1][nt][3]));
        Bout0[mtp][nt] = u0.v;
        Bout1[mtp][nt] = u1.v;
      }
    }
  }
}

// ---------------- fused main kernel: 1-wave blocks, 128 points/wave (2 tasks) ----------------
// (64,1): unconstrained VGPR budget (allocator law: budget = 2048/(waves x min_blocks);
// min_blocks>1 re-caps at 64 and spills — r15). Live set ~360 regs fits 512.
__global__ void __launch_bounds__(64, 1)
mlp_main(const float* __restrict__ xyz, const float* __restrict__ b1,
         const float* __restrict__ b2, const float* __restrict__ bout,
         const unsigned char* __restrict__ ws, float* __restrict__ out) {
  extern __shared__ char lds[];
  const int lane = threadIdx.x;
  const int g = lane >> 4, r16 = lane & 15;

  char* scr = lds;  // this wave's private transpose scratch (32 rows x 128B)
  const float bo = bout[0];

  const int pbase = blockIdx.x * 128;

  // ---- features for both 64-pt tasks: 39 xyz dims (tenc folded), HW trig ----
  f16x8 B0[2][2][4];  // [task][kt][nt]
  const float INV2PI = 0.15915494309189535f;
#pragma unroll
  for (int t = 0; t < 2; ++t) {
    const int p = pbase + t * 64 + lane;
    float ff[40];
    const float xs0 = xyz[p * 3], xs1 = xyz[p * 3 + 1], xs2 = xyz[p * 3 + 2];
    const float pcs[3] = {(xs0 + 1.f) * 0.5f, (xs1 + 1.f) * 0.5f, (xs2 + 1.f) * 0.5f};
#pragma unroll
    for (int c = 0; c < 3; ++c) {
      ff[c] = pcs[c];
      const float rev = pcs[c] * INV2PI;
      float s = hwsin_rev(rev), co = hwcos_rev(rev);
#pragma unroll
      for (int f = 0; f < 6; ++f) {
        ff[3 + f * 3 + c] = s;
        ff[21 + f * 3 + c] = co;
        const float s2 = 2.f * s * co, c2 = 1.f - 2.f * s * s;
        s = s2; co = c2;
      }
    }
    ff[39] = 0.f;
    unsigned int fw[32];
#pragma unroll
    for (int i = 0; i < 20; ++i) fw[i] = pkrtz(ff[2 * i], ff[2 * i + 1]);
#pragma unroll
    for (int i = 20; i < 32; ++i) fw[i] = 0u;

    // transpose via scratch, two 32-point halves (wave-internal sync)
#pragma unroll
    for (int h = 0; h < 2; ++h) {
      if ((lane >> 5) == h) {
#pragma unroll
        for (int s = 0; s < 8; ++s)
          *(u32x4*)(scr + (lane & 31) * 128 + ((s ^ (lane & 7)) * 16)) = ((const u32x4*)fw)[s];
      }
      asm volatile("s_waitcnt lgkmcnt(0)" ::: "memory");
#pragma unroll
      for (int kt = 0; kt < 2; ++kt)
#pragma unroll
        for (int nn = 0; nn < 2; ++nn) {
          const int row = nn * 16 + r16;
          B0[t][kt][h * 2 + nn] = *(const f16x8*)(scr + row * 128 + (((4 * kt + g) ^ (row & 7)) * 16));
        }
      asm volatile("s_waitcnt lgkmcnt(0)" ::: "memory");
    }
  }

  // ---- 3 hidden layers, dual-task, weights streamed once per wave ----
  const float* b0e = (const float*)(ws + B0E_OFF) + (blockIdx.x >> 8) * 128;  // batch = pbase/32768
  f16x8 Bx0[4][4], Bx1[4][4], By0[4][4], By1[4][4];
  layer_dual<2>(ws + W0P_OFF, b0e, B0[0], B0[1], Bx0, Bx1, lane);
  layer_dual<4>(ws + W1P_OFF, b1, Bx0, Bx1, By0, By1, lane);
  layer_dual<4>(ws + W2P_OFF, b2, By0, By1, Bx0, Bx1, lane);

  // ---- output layer (M=16 padded, row 0 real): 4 frags once, both tasks ----
  f16x8 Ab[4];
#pragma unroll
  for (int kt = 0; kt < 4; ++kt)
    Ab[kt] = *(const f16x8*)(ws + WOP_OFF + (kt * 64 + lane) * 16);
  const f32x4 bovec = (f32x4){bo, bo, bo, bo};
  f32x4 accO0[4], accO1[4];
  __builtin_amdgcn_s_setprio(1);
#pragma unroll
  for (int nt = 0; nt < 4; ++nt) {
    accO0[nt] = __builtin_amdgcn_mfma_f32_16x16x32_f16(Ab[0], Bx0[0][nt], bovec, 0, 0, 0);
    accO1[nt] = __builtin_amdgcn_mfma_f32_16x16x32_f16(Ab[0], Bx1[0][nt], bovec, 0, 0, 0);
  }
#pragma unroll
  for (int kt = 1; kt < 4; ++kt) {
#pragma unroll
    for (int nt = 0; nt < 4; ++nt) {
      accO0[nt] = __builtin_amdgcn_mfma_f32_16x16x32_f16(Ab[kt], Bx0[kt][nt], accO0[nt], 0, 0, 0);
      accO1[nt] = __builtin_amdgcn_mfma_f32_16x16x32_f16(Ab[kt], Bx1[kt][nt], accO1[nt], 0, 0, 0);
    }
  }
  __builtin_amdgcn_s_setprio(0);

  // ---- coalesced stores: broadcast row-0 values, one 256B wave store per task ----
  {
    const float a0 = __shfl(accO0[0][0], r16, 64);
    const float a1 = __shfl(accO0[1][0], r16, 64);
    const float a2 = __shfl(accO0[2][0], r16, 64);
    const float a3 = __shfl(accO0[3][0], r16, 64);
    out[pbase + lane] = g == 0 ? a0 : g == 1 ? a1 : g == 2 ? a2 : a3;
  }
  {
    const float a0 = __shfl(accO1[0][0], r16, 64);
    const float a1 = __shfl(accO1[1][0], r16, 64);
    const float a2 = __shfl(accO1[2][0], r16, 64);
    const float a3 = __shfl(accO1[3][0], r16, 64);
    out[pbase + 64 + lane] = g == 0 ? a0 : g == 1 ? a1 : g == 2 ? a2 : a3;
  }
}

extern "C" void kernel_launch(void* const* d_in, const int* in_sizes, int n_in,
                              void* d_out, int out_size, void* d_ws, size_t ws_size,
                              hipStream_t stream) {
  const float* time = (const float*)d_in[0];
  const float* xyz  = (const float*)d_in[1];
  const float* te0  = (const float*)d_in[2];
  const float* te1  = (const float*)d_in[3];
  const float* W0   = (const float*)d_in[4];
  const float* b0   = (const float*)d_in[5];
  const float* W1   = (const float*)d_in[6];
  const float* b1   = (const float*)d_in[7];
  const float* W2   = (const float*)d_in[8];
  const float* b2   = (const float*)d_in[9];
  const float* Wout = (const float*)d_in[10];
  const float* bout = (const float*)d_in[11];
  float* out = (float*)d_out;
  unsigned char* ws = (unsigned char*)d_ws;
  if (ws_size < WS_NEEDED) return;

  // 84 weight-frag blocks + 32 blocks computing b0_eff (16 batches x 128)
  pack_weights<<<116, 64, 0, stream>>>(time, te0, te1, W0, b0, W1, W2, Wout, ws);
  mlp_main<<<NPTS / 128, 64, LDS_TOTAL, stream>>>(xyz, b1, b2, bout, ws, out);
}

// Round 20
// 48.314 us; speedup vs baseline: 1.0650x; 1.0650x over previous
//
#include <hip/hip_runtime.h>

typedef _Float16 f16;
typedef __attribute__((ext_vector_type(2))) __fp16 fp16x2;
typedef __attribute__((ext_vector_type(8))) _Float16 f16x8;
typedef __attribute__((ext_vector_type(4))) float f32x4;
typedef __attribute__((ext_vector_type(4))) unsigned int u32x4;

#define NPTS   (16 * 32768)
// packed-weight layout in d_ws (bytes); weights stay in global (L2-resident, ~80KB)
#define W0P_OFF 0
#define W1P_OFF (16 * 1024)
#define W2P_OFF (48 * 1024)
#define WOP_OFF (80 * 1024)
#define FRAGS_BYTES (84 * 1024)
#define B0E_OFF FRAGS_BYTES           // in ws: 16 batches x 128 f32 effective layer-0 bias
#define WS_NEEDED (FRAGS_BYTES + 8192)
// LDS: one wave per block -> single 4KB transpose scratch
#define LDS_TOTAL 4096

// ---------------- pack kernel: weights -> f16 A-operand fragments (W^T) ----------------
// A frag (mt,kt) stored at index fi = mt*KT + kt: lane l, elem j <-> W_sw[m = 16mt + (l&15)][k]
//   layer0 (natural k-map): k = 32kt + 8*(l>>4) + j ; covers the 39 xyz dims
//     (orig W0 row = 16 + k; tenc rows folded into b0_eff, blocks 84..115)
//   layers 1,2,out (chained from D layout): k = 32kt + 16*(j>>2) + 4*(l>>4) + (j&3)
__global__ void pack_weights(const float* __restrict__ time, const float* __restrict__ te0,
                             const float* __restrict__ te1, const float* __restrict__ W0,
                             const float* __restrict__ b0, const float* __restrict__ W1,
                             const float* __restrict__ W2, const float* __restrict__ Wout,
                             unsigned char* __restrict__ ws) {
  const int bi = blockIdx.x;
  const int l = threadIdx.x;
  const int g = l >> 4, r16 = l & 15;
  if (bi < 84) {
    const float* W; int obase, fi, kt, mt, kmax; bool natural, outcol;
    if (bi < 16)      { W = W0;   fi = bi;      mt = fi >> 1; kt = fi & 1; obase = W0P_OFF; kmax = 39;  natural = true;  outcol = false; }
    else if (bi < 48) { W = W1;   fi = bi - 16; mt = fi >> 2; kt = fi & 3; obase = W1P_OFF; kmax = 128; natural = false; outcol = false; }
    else if (bi < 80) { W = W2;   fi = bi - 48; mt = fi >> 2; kt = fi & 3; obase = W2P_OFF; kmax = 128; natural = false; outcol = false; }
    else              { W = Wout; fi = bi - 80; mt = 0;       kt = fi;     obase = WOP_OFF; kmax = 128; natural = false; outcol = true;  }
    const int m = mt * 16 + r16;
    f16 vals[8] __attribute__((aligned(16)));
#pragma unroll
    for (int j = 0; j < 8; ++j) {
      const int k = natural ? (kt * 32 + g * 8 + j)
                            : (kt * 32 + (j >> 2) * 16 + g * 4 + (j & 3));
      float v = 0.f;
      if (k < kmax) {
        if (outcol)       v = (m == 0) ? Wout[k] : 0.f;
        else if (natural) v = W[(16 + k) * 128 + m];   // layer0: skip tenc rows
        else              v = W[k * 128 + m];
      }
      vals[j] = (f16)v;
    }
    *(u32x4*)(ws + obase + (fi * 64 + l) * 16) = *(const u32x4*)vals;
  } else {
    // b0_eff[b][m] = b0[m] + sum_d tenc[b][d] * W0[d][m],  d = 0..15 (orig rows)
    const int idx = (bi - 84) * 64 + l;  // 0..2047
    const int b = idx >> 7, m = idx & 127;
    const float t = time[b];
    float acc = b0[m];
#pragma unroll
    for (int d = 0; d < 16; ++d) {
      const float* emb; int L, dd;
      if (d < 8) { emb = te0; L = 5;  dd = d; }
      else       { emb = te1; L = 20; dd = d - 8; }
      const float tL = t * (float)L;
      int i = (int)floorf(tL);
      i = i < 0 ? 0 : (i > L - 1 ? L - 1 : i);
      const float wlo = (float)(i + 1) - tL;
      float v = wlo * emb[i * 8 + dd] + (1.f - wlo) * emb[(i + 1) * 8 + dd];
      if (t >= 1.f) v = emb[L * 8 + dd];
      acc += v * W0[d * 128 + m];
    }
    ((float*)(ws + B0E_OFF))[b * 128 + m] = acc;
  }
}

// packed relu: max of two f16 halves vs 0 (exact: relu commutes with RTZ rounding)
__device__ __forceinline__ unsigned int pkmax0(unsigned int x) {
  unsigned int r;
  asm("v_pk_max_f16 %0, %1, %2" : "=v"(r) : "v"(x), "v"(0u));
  return r;
}
__device__ __forceinline__ unsigned int pkrtz(float a, float b) {
  union { fp16x2 h; unsigned int u; } c;
  c.h = __builtin_amdgcn_cvt_pkrtz(a, b);
  return c.u;
}
// HW transcendentals: v_sin/v_cos take revolutions (input * 2pi). x in [0,1] here.
__device__ __forceinline__ float hwsin_rev(float rev) {
  float r; asm("v_sin_f32 %0, %1" : "=v"(r) : "v"(rev)); return r;
}
__device__ __forceinline__ float hwcos_rev(float rev) {
  float r; asm("v_cos_f32 %0, %1" : "=v"(r) : "v"(rev)); return r;
}

// ---------------- one swapped hidden layer, register-lean: D = W_sw(128xK) * Bin(Kx64) ----------------
// Single-strip accumulation: 8 serial 16-row m-strips, acc[4] (16 regs, was 32);
// 2-slot depth-1 A-frag prefetch (8 regs, was 24); one float4 bias per strip.
// Each strip's epilogue writes HALF of Bout[mt>>1][nt] (union RMW, compile-time lanes).
// Peak live ~145 regs (was ~180) -> more co-resident waves (the only lever that has
// ever moved duration: occupancy tracks perf across r15-r19).
template <int KT>
__device__ __forceinline__ void layer_swapped(const unsigned char* __restrict__ wsrc,
                                              const float* __restrict__ bias,
                                              const f16x8 (&Bin)[KT][4], f16x8 (&Bout)[4][4],
                                              int lane) {
  const int g4 = (lane >> 4) * 4;
  f16x8 Ab[2];
  Ab[0] = *(const f16x8*)(wsrc + (0 * 64 + lane) * 16);
#pragma unroll
  for (int mt = 0; mt < 8; ++mt) {
    const float4 bv = *(const float4*)(bias + mt * 16 + g4);
    f32x4 acc[4];
#pragma unroll
    for (int nt = 0; nt < 4; ++nt) acc[nt] = (f32x4){bv.x, bv.y, bv.z, bv.w};
#pragma unroll
    for (int kt = 0; kt < KT; ++kt) {
      const int s = mt * KT + kt;
      // depth-1 prefetch into the other slot (frag index fi == s by packing)
      if (s + 1 < 8 * KT)
        Ab[(s + 1) & 1] = *(const f16x8*)(wsrc + ((s + 1) * 64 + lane) * 16);
      __builtin_amdgcn_s_setprio(1);
#pragma unroll
      for (int nt = 0; nt < 4; ++nt)
        acc[nt] = __builtin_amdgcn_mfma_f32_16x16x32_f16(Ab[s & 1], Bin[kt][nt], acc[nt], 0, 0, 0);
      __builtin_amdgcn_s_setprio(0);
    }
    // epilogue: relu+pack, fill half of the destination fragment (strip parity)
#pragma unroll
    for (int nt = 0; nt < 4; ++nt) {
      union { f16x8 v; unsigned int w[4]; } ub;
      ub.v = Bout[mt >> 1][nt];
      ub.w[2 * (mt & 1) + 0] = pkmax0(pkrtz(acc[nt][0], acc[nt][1]));
      ub.w[2 * (mt & 1) + 1] = pkmax0(pkrtz(acc[nt][2], acc[nt][3]));
      Bout[mt >> 1][nt] = ub.v;
    }
  }
}

// ---------------- fused main kernel: SINGLE-WAVE blocks (64 thr), weights from L2 ----------------
// (64,1): unconstrained VGPR budget (allocator law: budget = 2048/(waves x min_blocks);
// any min_blocks>1 re-caps VGPR at 64 and spills — r15).
__global__ void __launch_bounds__(64, 1)
mlp_main(const float* __restrict__ xyz, const float* __restrict__ b1,
         const float* __restrict__ b2, const float* __restrict__ bout,
         const unsigned char* __restrict__ ws, float* __restrict__ out) {
  extern __shared__ char lds[];
  const int lane = threadIdx.x;
  const int g = lane >> 4, r16 = lane & 15;

  char* scr = lds;  // this wave's private transpose scratch (32 rows x 128B)
  const float bo = bout[0];

  const int pbase = blockIdx.x * 64;
  const int p = pbase + lane;

  // ---- 39-dim xyz feature row in f32 (tenc folded into b0_eff), pack with cvt_pkrtz ----
  // dim order: [pts(3), sin(18), cos(18)], zeros to 64. orig W0 row = 16 + dim.
  float ff[40];
  const float xs0 = xyz[p * 3], xs1 = xyz[p * 3 + 1], xs2 = xyz[p * 3 + 2];
  const float pcs[3] = {(xs0 + 1.f) * 0.5f, (xs1 + 1.f) * 0.5f, (xs2 + 1.f) * 0.5f};
  const float INV2PI = 0.15915494309189535f;
#pragma unroll
  for (int c = 0; c < 3; ++c) {
    ff[c] = pcs[c];
    const float rev = pcs[c] * INV2PI;
    float s = hwsin_rev(rev), co = hwcos_rev(rev);
#pragma unroll
    for (int f = 0; f < 6; ++f) {
      ff[3 + f * 3 + c] = s;
      ff[21 + f * 3 + c] = co;
      const float s2 = 2.f * s * co, c2 = 1.f - 2.f * s * s;
      s = s2; co = c2;
    }
  }
  ff[39] = 0.f;
  unsigned int fw[32];
#pragma unroll
  for (int i = 0; i < 20; ++i) fw[i] = pkrtz(ff[2 * i], ff[2 * i + 1]);
#pragma unroll
  for (int i = 20; i < 32; ++i) fw[i] = 0u;

  // ---- transpose via scratch, two 32-point halves (wave-internal sync) ----
  f16x8 B0[2][4];
#pragma unroll
  for (int h = 0; h < 2; ++h) {
    if ((lane >> 5) == h) {
#pragma unroll
      for (int s = 0; s < 8; ++s)
        *(u32x4*)(scr + (lane & 31) * 128 + ((s ^ (lane & 7)) * 16)) = ((const u32x4*)fw)[s];
    }
    asm volatile("s_waitcnt lgkmcnt(0)" ::: "memory");
#pragma unroll
    for (int kt = 0; kt < 2; ++kt)
#pragma unroll
      for (int nn = 0; nn < 2; ++nn) {
        const int row = nn * 16 + r16;
        B0[kt][h * 2 + nn] = *(const f16x8*)(scr + row * 128 + (((4 * kt + g) ^ (row & 7)) * 16));
      }
    asm volatile("s_waitcnt lgkmcnt(0)" ::: "memory");
  }

  // ---- 3 hidden layers fully in registers, weights streamed from L2 ----
  const float* b0e = (const float*)(ws + B0E_OFF) + (blockIdx.x >> 9) * 128;  // batch = p/32768
  f16x8 Bx[4][4], By[4][4];
  layer_swapped<2>(ws + W0P_OFF, b0e, B0, Bx, lane);
  layer_swapped<4>(ws + W1P_OFF, b1, Bx, By, lane);
  layer_swapped<4>(ws + W2P_OFF, b2, By, Bx, lane);

  // ---- output layer (M=16 padded, only row 0 real): 2-slot prefetch, bias as C ----
  f16x8 Ob[2];
  Ob[0] = *(const f16x8*)(ws + WOP_OFF + (0 * 64 + lane) * 16);
  const f32x4 bovec = (f32x4){bo, bo, bo, bo};
  f32x4 accO[4];
#pragma unroll
  for (int kt = 0; kt < 4; ++kt) {
    if (kt + 1 < 4)
      Ob[(kt + 1) & 1] = *(const f16x8*)(ws + WOP_OFF + ((kt + 1) * 64 + lane) * 16);
    __builtin_amdgcn_s_setprio(1);
    if (kt == 0) {
#pragma unroll
      for (int nt = 0; nt < 4; ++nt)
        accO[nt] = __builtin_amdgcn_mfma_f32_16x16x32_f16(Ob[0], Bx[0][nt], bovec, 0, 0, 0);
    } else {
#pragma unroll
      for (int nt = 0; nt < 4; ++nt)
        accO[nt] = __builtin_amdgcn_mfma_f32_16x16x32_f16(Ob[kt & 1], Bx[kt][nt], accO[nt], 0, 0, 0);
    }
    __builtin_amdgcn_s_setprio(0);
  }

  // ---- coalesced store: broadcast row-0 values, one 256B wave store ----
  const float a0 = __shfl(accO[0][0], r16, 64);
  const float a1 = __shfl(accO[1][0], r16, 64);
  const float a2 = __shfl(accO[2][0], r16, 64);
  const float a3 = __shfl(accO[3][0], r16, 64);
  const float v = g == 0 ? a0 : g == 1 ? a1 : g == 2 ? a2 : a3;
  out[pbase + lane] = v;
}

extern "C" void kernel_launch(void* const* d_in, const int* in_sizes, int n_in,
                              void* d_out, int out_size, void* d_ws, size_t ws_size,
                              hipStream_t stream) {
  const float* time = (const float*)d_in[0];
  const float* xyz  = (const float*)d_in[1];
  const float* te0  = (const float*)d_in[2];
  const float* te1  = (const float*)d_in[3];
  const float* W0   = (const float*)d_in[4];
  const float* b0   = (const float*)d_in[5];
  const float* W1   = (const float*)d_in[6];
  const float* b1   = (const float*)d_in[7];
  const float* W2   = (const float*)d_in[8];
  const float* b2   = (const float*)d_in[9];
  const float* Wout = (const float*)d_in[10];
  const float* bout = (const float*)d_in[11];
  float* out = (float*)d_out;
  unsigned char* ws = (unsigned char*)d_ws;
  if (ws_size < WS_NEEDED) return;

  // 84 weight-frag blocks + 32 blocks computing b0_eff (16 batches x 128)
  pack_weights<<<116, 64, 0, stream>>>(time, te0, te1, W0, b0, W1, W2, Wout, ws);
  mlp_main<<<NPTS / 64, 64, LDS_TOTAL, stream>>>(xyz, b1, b2, bout, ws, out);
}

// Round 21
// 45.068 us; speedup vs baseline: 1.1417x; 1.0720x over previous
//
#include <hip/hip_runtime.h>

typedef _Float16 f16;
typedef __attribute__((ext_vector_type(2))) __fp16 fp16x2;
typedef __attribute__((ext_vector_type(8))) _Float16 f16x8;
typedef __attribute__((ext_vector_type(4))) float f32x4;
typedef __attribute__((ext_vector_type(4))) unsigned int u32x4;

#define NPTS   (16 * 32768)
// packed-weight layout in d_ws (bytes); weights stay in global (L2-resident, ~80KB)
#define W0P_OFF 0
#define W1P_OFF (16 * 1024)
#define W2P_OFF (48 * 1024)
#define WOP_OFF (80 * 1024)
#define FRAGS_BYTES (84 * 1024)
#define B0E_OFF FRAGS_BYTES           // in ws: 16 batches x 128 f32 effective layer-0 bias
#define WS_NEEDED (FRAGS_BYTES + 8192)
// LDS: one wave per block -> single 4KB transpose scratch
#define LDS_TOTAL 4096

// ---------------- pack kernel: weights -> f16 A-operand fragments (W^T) ----------------
// A frag (mt,kt) stored at index fi = mt*KT + kt: lane l, elem j <-> W_sw[m = 16mt + (l&15)][k]
//   layer0 (natural k-map): k = 32kt + 8*(l>>4) + j ; covers the 39 xyz dims
//     (orig W0 row = 16 + k; tenc rows folded into b0_eff, blocks 84..115)
//   layers 1,2,out (chained from D layout): k = 32kt + 16*(j>>2) + 4*(l>>4) + (j&3)
__global__ void pack_weights(const float* __restrict__ time, const float* __restrict__ te0,
                             const float* __restrict__ te1, const float* __restrict__ W0,
                             const float* __restrict__ b0, const float* __restrict__ W1,
                             const float* __restrict__ W2, const float* __restrict__ Wout,
                             unsigned char* __restrict__ ws) {
  const int bi = blockIdx.x;
  const int l = threadIdx.x;
  const int g = l >> 4, r16 = l & 15;
  if (bi < 84) {
    const float* W; int obase, fi, kt, mt, kmax; bool natural, outcol;
    if (bi < 16)      { W = W0;   fi = bi;      mt = fi >> 1; kt = fi & 1; obase = W0P_OFF; kmax = 39;  natural = true;  outcol = false; }
    else if (bi < 48) { W = W1;   fi = bi - 16; mt = fi >> 2; kt = fi & 3; obase = W1P_OFF; kmax = 128; natural = false; outcol = false; }
    else if (bi < 80) { W = W2;   fi = bi - 48; mt = fi >> 2; kt = fi & 3; obase = W2P_OFF; kmax = 128; natural = false; outcol = false; }
    else              { W = Wout; fi = bi - 80; mt = 0;       kt = fi;     obase = WOP_OFF; kmax = 128; natural = false; outcol = true;  }
    const int m = mt * 16 + r16;
    f16 vals[8] __attribute__((aligned(16)));
#pragma unroll
    for (int j = 0; j < 8; ++j) {
      const int k = natural ? (kt * 32 + g * 8 + j)
                            : (kt * 32 + (j >> 2) * 16 + g * 4 + (j & 3));
      float v = 0.f;
      if (k < kmax) {
        if (outcol)       v = (m == 0) ? Wout[k] : 0.f;
        else if (natural) v = W[(16 + k) * 128 + m];   // layer0: skip tenc rows
        else              v = W[k * 128 + m];
      }
      vals[j] = (f16)v;
    }
    *(u32x4*)(ws + obase + (fi * 64 + l) * 16) = *(const u32x4*)vals;
  } else {
    // b0_eff[b][m] = b0[m] + sum_d tenc[b][d] * W0[d][m],  d = 0..15 (orig rows)
    const int idx = (bi - 84) * 64 + l;  // 0..2047
    const int b = idx >> 7, m = idx & 127;
    const float t = time[b];
    float acc = b0[m];
#pragma unroll
    for (int d = 0; d < 16; ++d) {
      const float* emb; int L, dd;
      if (d < 8) { emb = te0; L = 5;  dd = d; }
      else       { emb = te1; L = 20; dd = d - 8; }
      const float tL = t * (float)L;
      int i = (int)floorf(tL);
      i = i < 0 ? 0 : (i > L - 1 ? L - 1 : i);
      const float wlo = (float)(i + 1) - tL;
      float v = wlo * emb[i * 8 + dd] + (1.f - wlo) * emb[(i + 1) * 8 + dd];
      if (t >= 1.f) v = emb[L * 8 + dd];
      acc += v * W0[d * 128 + m];
    }
    ((float*)(ws + B0E_OFF))[b * 128 + m] = acc;
  }
}

// packed relu: max of two f16 halves vs 0 (exact: relu commutes with RTZ rounding)
__device__ __forceinline__ unsigned int pkmax0(unsigned int x) {
  unsigned int r;
  asm("v_pk_max_f16 %0, %1, %2" : "=v"(r) : "v"(x), "v"(0u));
  return r;
}
__device__ __forceinline__ unsigned int pkrtz(float a, float b) {
  union { fp16x2 h; unsigned int u; } c;
  c.h = __builtin_amdgcn_cvt_pkrtz(a, b);
  return c.u;
}
// HW transcendentals: v_sin/v_cos take revolutions (input * 2pi). x in [0,1] here.
__device__ __forceinline__ float hwsin_rev(float rev) {
  float r; asm("v_sin_f32 %0, %1" : "=v"(r) : "v"(rev)); return r;
}
__device__ __forceinline__ float hwcos_rev(float rev) {
  float r; asm("v_cos_f32 %0, %1" : "=v"(r) : "v"(rev)); return r;
}

// ---------------- one swapped hidden layer, register-lean: D = W_sw(128xK) * Bin(Kx64) ----------------
// Single-strip accumulation (8 serial 16-row m-strips, acc[4]); 3-slot depth-2 A-frag
// prefetch (r8-proven distance); one float4 bias per strip as C-init; epilogue fills
// half of Bout[mt>>1][nt] per strip (union RMW, all lanes compile-time).
template <int KT>
__device__ __forceinline__ void layer_swapped(const unsigned char* __restrict__ wsrc,
                                              const float* __restrict__ bias,
                                              const f16x8 (&Bin)[KT][4], f16x8 (&Bout)[4][4],
                                              int lane) {
  const int g4 = (lane >> 4) * 4;
  f16x8 Ab[3];
  Ab[0] = *(const f16x8*)(wsrc + (0 * 64 + lane) * 16);
  Ab[1] = *(const f16x8*)(wsrc + (1 * 64 + lane) * 16);
#pragma unroll
  for (int mt = 0; mt < 8; ++mt) {
    const float4 bv = *(const float4*)(bias + mt * 16 + g4);
    f32x4 acc[4];
#pragma unroll
    for (int nt = 0; nt < 4; ++nt) acc[nt] = (f32x4){bv.x, bv.y, bv.z, bv.w};
#pragma unroll
    for (int kt = 0; kt < KT; ++kt) {
      const int s = mt * KT + kt;
      // depth-2 prefetch (frag index fi == s by packing)
      if (s + 2 < 8 * KT)
        Ab[(s + 2) % 3] = *(const f16x8*)(wsrc + ((s + 2) * 64 + lane) * 16);
      __builtin_amdgcn_s_setprio(1);
#pragma unroll
      for (int nt = 0; nt < 4; ++nt)
        acc[nt] = __builtin_amdgcn_mfma_f32_16x16x32_f16(Ab[s % 3], Bin[kt][nt], acc[nt], 0, 0, 0);
      __builtin_amdgcn_s_setprio(0);
    }
    // epilogue: relu+pack, fill half of the destination fragment (strip parity)
#pragma unroll
    for (int nt = 0; nt < 4; ++nt) {
      union { f16x8 v; unsigned int w[4]; } ub;
      ub.v = Bout[mt >> 1][nt];
      ub.w[2 * (mt & 1) + 0] = pkmax0(pkrtz(acc[nt][0], acc[nt][1]));
      ub.w[2 * (mt & 1) + 1] = pkmax0(pkrtz(acc[nt][2], acc[nt][3]));
      Bout[mt >> 1][nt] = ub.v;
    }
  }
}

// ---------------- fused main kernel: SINGLE-WAVE blocks (64 thr), weights from L2 ----------------
// __launch_bounds__(64, 3): unified-file law (refit r0..r20): total regs/wave =
// 512 / waves_per_EU, split VGPR+AGPR. (64,1) gave 512 -> allocator padded AGPRs to
// ~244/wave -> 2 waves/SIMD. (64,4) = 128 cap < live ~145 -> cliff spill (r15).
// (64,3) = ~170 cap >= live -> zero spill AND 3 waves/SIMD (12/CU, ~37% occ).
// Tripwire: FETCH >> 3.5MB means the allocator cliffed anyway -> revert to (64,1).
__global__ void __launch_bounds__(64, 3)
mlp_main(const float* __restrict__ xyz, const float* __restrict__ b1,
         const float* __restrict__ b2, const float* __restrict__ bout,
         const unsigned char* __restrict__ ws, float* __restrict__ out) {
  extern __shared__ char lds[];
  const int lane = threadIdx.x;
  const int g = lane >> 4, r16 = lane & 15;

  char* scr = lds;  // this wave's private transpose scratch (32 rows x 128B)
  const float bo = bout[0];

  const int pbase = blockIdx.x * 64;
  const int p = pbase + lane;

  // ---- 39-dim xyz feature row in f32 (tenc folded into b0_eff), pack with cvt_pkrtz ----
  // dim order: [pts(3), sin(18), cos(18)], zeros to 64. orig W0 row = 16 + dim.
  float ff[40];
  const float xs0 = xyz[p * 3], xs1 = xyz[p * 3 + 1], xs2 = xyz[p * 3 + 2];
  const float pcs[3] = {(xs0 + 1.f) * 0.5f, (xs1 + 1.f) * 0.5f, (xs2 + 1.f) * 0.5f};
  const float INV2PI = 0.15915494309189535f;
#pragma unroll
  for (int c = 0; c < 3; ++c) {
    ff[c] = pcs[c];
    const float rev = pcs[c] * INV2PI;
    float s = hwsin_rev(rev), co = hwcos_rev(rev);
#pragma unroll
    for (int f = 0; f < 6; ++f) {
      ff[3 + f * 3 + c] = s;
      ff[21 + f * 3 + c] = co;
      const float s2 = 2.f * s * co, c2 = 1.f - 2.f * s * s;
      s = s2; co = c2;
    }
  }
  ff[39] = 0.f;
  unsigned int fw[32];
#pragma unroll
  for (int i = 0; i < 20; ++i) fw[i] = pkrtz(ff[2 * i], ff[2 * i + 1]);
#pragma unroll
  for (int i = 20; i < 32; ++i) fw[i] = 0u;

  // ---- transpose via scratch, two 32-point halves (wave-internal sync) ----
  f16x8 B0[2][4];
#pragma unroll
  for (int h = 0; h < 2; ++h) {
    if ((lane >> 5) == h) {
#pragma unroll
      for (int s = 0; s < 8; ++s)
        *(u32x4*)(scr + (lane & 31) * 128 + ((s ^ (lane & 7)) * 16)) = ((const u32x4*)fw)[s];
    }
    asm volatile("s_waitcnt lgkmcnt(0)" ::: "memory");
#pragma unroll
    for (int kt = 0; kt < 2; ++kt)
#pragma unroll
      for (int nn = 0; nn < 2; ++nn) {
        const int row = nn * 16 + r16;
        B0[kt][h * 2 + nn] = *(const f16x8*)(scr + row * 128 + (((4 * kt + g) ^ (row & 7)) * 16));
      }
    asm volatile("s_waitcnt lgkmcnt(0)" ::: "memory");
  }

  // ---- 3 hidden layers fully in registers, weights streamed from L2 ----
  const float* b0e = (const float*)(ws + B0E_OFF) + (blockIdx.x >> 9) * 128;  // batch = p/32768
  f16x8 Bx[4][4], By[4][4];
  layer_swapped<2>(ws + W0P_OFF, b0e, B0, Bx, lane);
  layer_swapped<4>(ws + W1P_OFF, b1, Bx, By, lane);
  layer_swapped<4>(ws + W2P_OFF, b2, By, Bx, lane);

  // ---- output layer (M=16 padded, only row 0 real): 2-slot prefetch, bias as C ----
  f16x8 Ob[2];
  Ob[0] = *(const f16x8*)(ws + WOP_OFF + (0 * 64 + lane) * 16);
  const f32x4 bovec = (f32x4){bo, bo, bo, bo};
  f32x4 accO[4];
#pragma unroll
  for (int kt = 0; kt < 4; ++kt) {
    if (kt + 1 < 4)
      Ob[(kt + 1) & 1] = *(const f16x8*)(ws + WOP_OFF + ((kt + 1) * 64 + lane) * 16);
    __builtin_amdgcn_s_setprio(1);
    if (kt == 0) {
#pragma unroll
      for (int nt = 0; nt < 4; ++nt)
        accO[nt] = __builtin_amdgcn_mfma_f32_16x16x32_f16(Ob[0], Bx[0][nt], bovec, 0, 0, 0);
    } else {
#pragma unroll
      for (int nt = 0; nt < 4; ++nt)
        accO[nt] = __builtin_amdgcn_mfma_f32_16x16x32_f16(Ob[kt & 1], Bx[kt][nt], accO[nt], 0, 0, 0);
    }
    __builtin_amdgcn_s_setprio(0);
  }

  // ---- coalesced store: broadcast row-0 values, one 256B wave store ----
  const float a0 = __shfl(accO[0][0], r16, 64);
  const float a1 = __shfl(accO[1][0], r16, 64);
  const float a2 = __shfl(accO[2][0], r16, 64);
  const float a3 = __shfl(accO[3][0], r16, 64);
  const float v = g == 0 ? a0 : g == 1 ? a1 : g == 2 ? a2 : a3;
  out[pbase + lane] = v;
}

extern "C" void kernel_launch(void* const* d_in, const int* in_sizes, int n_in,
                              void* d_out, int out_size, void* d_ws, size_t ws_size,
                              hipStream_t stream) {
  const float* time = (const float*)d_in[0];
  const float* xyz  = (const float*)d_in[1];
  const float* te0  = (const float*)d_in[2];
  const float* te1  = (const float*)d_in[3];
  const float* W0   = (const float*)d_in[4];
  const float* b0   = (const float*)d_in[5];
  const float* W1   = (const float*)d_in[6];
  const float* b1   = (const float*)d_in[7];
  const float* W2   = (const float*)d_in[8];
  const float* b2   = (const float*)d_in[9];
  const float* Wout = (const float*)d_in[10];
  const float* bout = (const float*)d_in[11];
  float* out = (float*)d_out;
  unsigned char* ws = (unsigned char*)d_ws;
  if (ws_size < WS_NEEDED) return;

  // 84 weight-frag blocks + 32 blocks computing b0_eff (16 batches x 128)
  pack_weights<<<116, 64, 0, stream>>>(time, te0, te1, W0, b0, W1, W2, Wout, ws);
  mlp_main<<<NPTS / 64, 64, LDS_TOTAL, stream>>>(xyz, b1, b2, bout, ws, out);
}

// Round 22
// 44.211 us; speedup vs baseline: 1.1638x; 1.0194x over previous
//
#include <hip/hip_runtime.h>

typedef _Float16 f16;
typedef __attribute__((ext_vector_type(2))) __fp16 fp16x2;
typedef __attribute__((ext_vector_type(8))) _Float16 f16x8;
typedef __attribute__((ext_vector_type(4))) float f32x4;
typedef __attribute__((ext_vector_type(4))) unsigned int u32x4;

#define NPTS   (16 * 32768)
// packed-weight layout in d_ws (bytes); weights stay in global (L2-resident, ~80KB)
#define W0P_OFF 0
#define W1P_OFF (16 * 1024)
#define W2P_OFF (48 * 1024)
#define WOP_OFF (80 * 1024)
#define FRAGS_BYTES (84 * 1024)
#define B0E_OFF FRAGS_BYTES           // in ws: 16 batches x 128 f32 effective layer-0 bias
#define WS_NEEDED (FRAGS_BYTES + 8192)
// LDS: one wave per block -> single 4KB transpose scratch
#define LDS_TOTAL 4096

// ---------------- pack kernel: weights -> f16 A-operand fragments (W^T) ----------------
// A frag (mt,kt) stored at index fi = mt*KT + kt: lane l, elem j <-> W_sw[m = 16mt + (l&15)][k]
//   layer0 (natural k-map): k = 32kt + 8*(l>>4) + j ; covers the 39 xyz dims
//     (orig W0 row = 16 + k; tenc rows folded into b0_eff, blocks 84..115)
//   layers 1,2,out (chained from D layout): k = 32kt + 16*(j>>2) + 4*(l>>4) + (j&3)
__global__ void pack_weights(const float* __restrict__ time, const float* __restrict__ te0,
                             const float* __restrict__ te1, const float* __restrict__ W0,
                             const float* __restrict__ b0, const float* __restrict__ W1,
                             const float* __restrict__ W2, const float* __restrict__ Wout,
                             unsigned char* __restrict__ ws) {
  const int bi = blockIdx.x;
  const int l = threadIdx.x;
  const int g = l >> 4, r16 = l & 15;
  if (bi < 84) {
    const float* W; int obase, fi, kt, mt, kmax; bool natural, outcol;
    if (bi < 16)      { W = W0;   fi = bi;      mt = fi >> 1; kt = fi & 1; obase = W0P_OFF; kmax = 39;  natural = true;  outcol = false; }
    else if (bi < 48) { W = W1;   fi = bi - 16; mt = fi >> 2; kt = fi & 3; obase = W1P_OFF; kmax = 128; natural = false; outcol = false; }
    else if (bi < 80) { W = W2;   fi = bi - 48; mt = fi >> 2; kt = fi & 3; obase = W2P_OFF; kmax = 128; natural = false; outcol = false; }
    else              { W = Wout; fi = bi - 80; mt = 0;       kt = fi;     obase = WOP_OFF; kmax = 128; natural = false; outcol = true;  }
    const int m = mt * 16 + r16;
    f16 vals[8] __attribute__((aligned(16)));
#pragma unroll
    for (int j = 0; j < 8; ++j) {
      const int k = natural ? (kt * 32 + g * 8 + j)
                            : (kt * 32 + (j >> 2) * 16 + g * 4 + (j & 3));
      float v = 0.f;
      if (k < kmax) {
        if (outcol)       v = (m == 0) ? Wout[k] : 0.f;
        else if (natural) v = W[(16 + k) * 128 + m];   // layer0: skip tenc rows
        else              v = W[k * 128 + m];
      }
      vals[j] = (f16)v;
    }
    *(u32x4*)(ws + obase + (fi * 64 + l) * 16) = *(const u32x4*)vals;
  } else {
    // b0_eff[b][m] = b0[m] + sum_d tenc[b][d] * W0[d][m],  d = 0..15 (orig rows)
    const int idx = (bi - 84) * 64 + l;  // 0..2047
    const int b = idx >> 7, m = idx & 127;
    const float t = time[b];
    float acc = b0[m];
#pragma unroll
    for (int d = 0; d < 16; ++d) {
      const float* emb; int L, dd;
      if (d < 8) { emb = te0; L = 5;  dd = d; }
      else       { emb = te1; L = 20; dd = d - 8; }
      const float tL = t * (float)L;
      int i = (int)floorf(tL);
      i = i < 0 ? 0 : (i > L - 1 ? L - 1 : i);
      const float wlo = (float)(i + 1) - tL;
      float v = wlo * emb[i * 8 + dd] + (1.f - wlo) * emb[(i + 1) * 8 + dd];
      if (t >= 1.f) v = emb[L * 8 + dd];
      acc += v * W0[d * 128 + m];
    }
    ((float*)(ws + B0E_OFF))[b * 128 + m] = acc;
  }
}

// packed relu: max of two f16 halves vs 0 (exact: relu commutes with RTZ rounding)
__device__ __forceinline__ unsigned int pkmax0(unsigned int x) {
  unsigned int r;
  asm("v_pk_max_f16 %0, %1, %2" : "=v"(r) : "v"(x), "v"(0u));
  return r;
}
__device__ __forceinline__ unsigned int pkrtz(float a, float b) {
  union { fp16x2 h; unsigned int u; } c;
  c.h = __builtin_amdgcn_cvt_pkrtz(a, b);
  return c.u;
}
// HW transcendentals: v_sin/v_cos take revolutions (input * 2pi). x in [0,1] here.
__device__ __forceinline__ float hwsin_rev(float rev) {
  float r; asm("v_sin_f32 %0, %1" : "=v"(r) : "v"(rev)); return r;
}
__device__ __forceinline__ float hwcos_rev(float rev) {
  float r; asm("v_cos_f32 %0, %1" : "=v"(r) : "v"(rev)); return r;
}

// ---------------- one swapped hidden layer, register-lean: D = W_sw(128xK) * Bin(Kx64) ----------------
// Single-strip accumulation (8 serial 16-row m-strips, acc[4]); 5-slot DEPTH-4 A-frag
// prefetch (short-step regime: 4-MFMA steps expose more load-wait than r8's long steps,
// so the r11 depth-null doesn't transfer — rule #23); one float4 bias per strip as
// C-init; epilogue fills half of Bout[mt>>1][nt] per strip (union RMW, compile-time).
template <int KT>
__device__ __forceinline__ void layer_swapped(const unsigned char* __restrict__ wsrc,
                                              const float* __restrict__ bias,
                                              const f16x8 (&Bin)[KT][4], f16x8 (&Bout)[4][4],
                                              int lane) {
  const int g4 = (lane >> 4) * 4;
  f16x8 Ab[5];
#pragma unroll
  for (int s = 0; s < 4; ++s)
    Ab[s] = *(const f16x8*)(wsrc + (s * 64 + lane) * 16);
#pragma unroll
  for (int mt = 0; mt < 8; ++mt) {
    const float4 bv = *(const float4*)(bias + mt * 16 + g4);
    f32x4 acc[4];
#pragma unroll
    for (int nt = 0; nt < 4; ++nt) acc[nt] = (f32x4){bv.x, bv.y, bv.z, bv.w};
#pragma unroll
    for (int kt = 0; kt < KT; ++kt) {
      const int s = mt * KT + kt;
      // depth-4 prefetch (frag index fi == s by packing); slot (s+4)%5 freed at s-1
      if (s + 4 < 8 * KT)
        Ab[(s + 4) % 5] = *(const f16x8*)(wsrc + ((s + 4) * 64 + lane) * 16);
      __builtin_amdgcn_s_setprio(1);
#pragma unroll
      for (int nt = 0; nt < 4; ++nt)
        acc[nt] = __builtin_amdgcn_mfma_f32_16x16x32_f16(Ab[s % 5], Bin[kt][nt], acc[nt], 0, 0, 0);
      __builtin_amdgcn_s_setprio(0);
    }
    // epilogue: relu+pack, fill half of the destination fragment (strip parity)
#pragma unroll
    for (int nt = 0; nt < 4; ++nt) {
      union { f16x8 v; unsigned int w[4]; } ub;
      ub.v = Bout[mt >> 1][nt];
      ub.w[2 * (mt & 1) + 0] = pkmax0(pkrtz(acc[nt][0], acc[nt][1]));
      ub.w[2 * (mt & 1) + 1] = pkmax0(pkrtz(acc[nt][2], acc[nt][3]));
      Bout[mt >> 1][nt] = ub.v;
    }
  }
}

// ---------------- fused main kernel: SINGLE-WAVE blocks (64 thr), weights from L2 ----------------
// __launch_bounds__(64, 3): caps total (VGPR+AGPR) at ~512/3 ~= 170/wave. r21 evidence:
// this stops lazy AGPR padding (accvgpr shuffle ops gone -> VALUBusy 33->28) and
// tightened issue density (MfmaUtil 34->40, steady 55.8->46.6us). Live ~158 fits.
// Tripwire: FETCH >> 3.5MB = cap cliff -> revert depth to 2.
__global__ void __launch_bounds__(64, 3)
mlp_main(const float* __restrict__ xyz, const float* __restrict__ b1,
         const float* __restrict__ b2, const float* __restrict__ bout,
         const unsigned char* __restrict__ ws, float* __restrict__ out) {
  extern __shared__ char lds[];
  const int lane = threadIdx.x;
  const int g = lane >> 4, r16 = lane & 15;

  char* scr = lds;  // this wave's private transpose scratch (32 rows x 128B)
  const float bo = bout[0];

  const int pbase = blockIdx.x * 64;
  const int p = pbase + lane;

  // ---- 39-dim xyz feature row in f32 (tenc folded into b0_eff), pack with cvt_pkrtz ----
  // dim order: [pts(3), sin(18), cos(18)], zeros to 64. orig W0 row = 16 + dim.
  float ff[40];
  const float xs0 = xyz[p * 3], xs1 = xyz[p * 3 + 1], xs2 = xyz[p * 3 + 2];
  const float pcs[3] = {(xs0 + 1.f) * 0.5f, (xs1 + 1.f) * 0.5f, (xs2 + 1.f) * 0.5f};
  const float INV2PI = 0.15915494309189535f;
#pragma unroll
  for (int c = 0; c < 3; ++c) {
    ff[c] = pcs[c];
    const float rev = pcs[c] * INV2PI;
    float s = hwsin_rev(rev), co = hwcos_rev(rev);
#pragma unroll
    for (int f = 0; f < 6; ++f) {
      ff[3 + f * 3 + c] = s;
      ff[21 + f * 3 + c] = co;
      const float s2 = 2.f * s * co, c2 = 1.f - 2.f * s * s;
      s = s2; co = c2;
    }
  }
  ff[39] = 0.f;
  unsigned int fw[32];
#pragma unroll
  for (int i = 0; i < 20; ++i) fw[i] = pkrtz(ff[2 * i], ff[2 * i + 1]);
#pragma unroll
  for (int i = 20; i < 32; ++i) fw[i] = 0u;

  // ---- transpose via scratch, two 32-point halves (wave-internal sync) ----
  f16x8 B0[2][4];
#pragma unroll
  for (int h = 0; h < 2; ++h) {
    if ((lane >> 5) == h) {
#pragma unroll
      for (int s = 0; s < 8; ++s)
        *(u32x4*)(scr + (lane & 31) * 128 + ((s ^ (lane & 7)) * 16)) = ((const u32x4*)fw)[s];
    }
    asm volatile("s_waitcnt lgkmcnt(0)" ::: "memory");
#pragma unroll
    for (int kt = 0; kt < 2; ++kt)
#pragma unroll
      for (int nn = 0; nn < 2; ++nn) {
        const int row = nn * 16 + r16;
        B0[kt][h * 2 + nn] = *(const f16x8*)(scr + row * 128 + (((4 * kt + g) ^ (row & 7)) * 16));
      }
    asm volatile("s_waitcnt lgkmcnt(0)" ::: "memory");
  }

  // ---- 3 hidden layers fully in registers, weights streamed from L2 ----
  const float* b0e = (const float*)(ws + B0E_OFF) + (blockIdx.x >> 9) * 128;  // batch = p/32768
  f16x8 Bx[4][4], By[4][4];
  layer_swapped<2>(ws + W0P_OFF, b0e, B0, Bx, lane);
  layer_swapped<4>(ws + W1P_OFF, b1, Bx, By, lane);
  layer_swapped<4>(ws + W2P_OFF, b2, By, Bx, lane);

  // ---- output layer (M=16 padded, only row 0 real): preload all 4 frags, bias as C ----
  f16x8 Ob[4];
#pragma unroll
  for (int kt = 0; kt < 4; ++kt)
    Ob[kt] = *(const f16x8*)(ws + WOP_OFF + (kt * 64 + lane) * 16);
  const f32x4 bovec = (f32x4){bo, bo, bo, bo};
  f32x4 accO[4];
  __builtin_amdgcn_s_setprio(1);
#pragma unroll
  for (int nt = 0; nt < 4; ++nt)
    accO[nt] = __builtin_amdgcn_mfma_f32_16x16x32_f16(Ob[0], Bx[0][nt], bovec, 0, 0, 0);
#pragma unroll
  for (int kt = 1; kt < 4; ++kt) {
#pragma unroll
    for (int nt = 0; nt < 4; ++nt)
      accO[nt] = __builtin_amdgcn_mfma_f32_16x16x32_f16(Ob[kt], Bx[kt][nt], accO[nt], 0, 0, 0);
  }
  __builtin_amdgcn_s_setprio(0);

  // ---- coalesced store: broadcast row-0 values, one 256B wave store ----
  const float a0 = __shfl(accO[0][0], r16, 64);
  const float a1 = __shfl(accO[1][0], r16, 64);
  const float a2 = __shfl(accO[2][0], r16, 64);
  const float a3 = __shfl(accO[3][0], r16, 64);
  const float v = g == 0 ? a0 : g == 1 ? a1 : g == 2 ? a2 : a3;
  out[pbase + lane] = v;
}

extern "C" void kernel_launch(void* const* d_in, const int* in_sizes, int n_in,
                              void* d_out, int out_size, void* d_ws, size_t ws_size,
                              hipStream_t stream) {
  const float* time = (const float*)d_in[0];
  const float* xyz  = (const float*)d_in[1];
  const float* te0  = (const float*)d_in[2];
  const float* te1  = (const float*)d_in[3];
  const float* W0   = (const float*)d_in[4];
  const float* b0   = (const float*)d_in[5];
  const float* W1   = (const float*)d_in[6];
  const float* b1   = (const float*)d_in[7];
  const float* W2   = (const float*)d_in[8];
  const float* b2   = (const float*)d_in[9];
  const float* Wout = (const float*)d_in[10];
  const float* bout = (const float*)d_in[11];
  float* out = (float*)d_out;
  unsigned char* ws = (unsigned char*)d_ws;
  if (ws_size < WS_NEEDED) return;

  // 84 weight-frag blocks + 32 blocks computing b0_eff (16 batches x 128)
  pack_weights<<<116, 64, 0, stream>>>(time, te0, te1, W0, b0, W1, W2, Wout, ws);
  mlp_main<<<NPTS / 64, 64, LDS_TOTAL, stream>>>(xyz, b1, b2, bout, ws, out);
}